// Round 1
// baseline (1072.416 us; speedup 1.0000x reference)
//
#include <hip/hip_runtime.h>

#define B_   16
#define D_   512
#define T_   2000
#define Q_   8
#define CD_  8
#define CS_  1024
#define NCOL 32000   // B_*T_

// workspace float offsets
#define WS_Z0   0              // 64*32000 = 2048000
#define WS_ZQ   2048000        // 64*32000 = 2048000
#define WS_M    4096000        // 64*64    = 4096
#define WS_VBP  4100096        // 8*8*8    = 512
#define WS_LP   4100608        // 8*500*2  = 8000

// d_out float offsets (quantized_out, all_idx, all_loss, all_q)
#define OFF_QOUT 0
#define OFF_IDX  16384000
#define OFF_LOSS 16640000
#define OFF_ALLQ 16640008

// ---------------- K_M: M[q][p][c][c'] = sum_d Wi[q,c,d] * Wo[p,d,c'] ----------------
__global__ void k_precompute_M(const float* __restrict__ Wi, const float* __restrict__ Wo,
                               float* __restrict__ ws) {
    int q = blockIdx.x >> 3, p = blockIdx.x & 7;
    int c = threadIdx.x >> 3, cp = threadIdx.x & 7;
    const float* wir = Wi + (q * CD_ + c) * D_;
    const float* wop = Wo + p * (D_ * CD_) + cp;
    double acc = 0.0;
    #pragma unroll 4
    for (int d = 0; d < D_; ++d) acc += (double)wir[d] * (double)wop[d * CD_];
    ws[WS_M + (q * 8 + p) * 64 + c * 8 + cp] = (float)acc;
}

// ---------------- K_vbp: vbp[q][p][c] = sum_d Wi[q,c,d] * bo[p,d] ----------------
__global__ void k_precompute_vbp(const float* __restrict__ Wi, const float* __restrict__ bo,
                                 float* __restrict__ ws) {
    int q = blockIdx.x >> 3, p = blockIdx.x & 7;
    int c = threadIdx.x >> 3, ds = threadIdx.x & 7;
    double a = 0.0;
    if (p < q) {
        const float* wir = Wi + (q * CD_ + c) * D_;
        const float* bop = bo + p * D_;
        for (int d = ds; d < D_; d += 8) a += (double)wir[d] * (double)bop[d];
    }
    a += __shfl_xor(a, 1);
    a += __shfl_xor(a, 2);
    a += __shfl_xor(a, 4);
    if (ds == 0) ws[WS_VBP + (q * 8 + p) * 8 + c] = (float)a;
}

// ---------------- K_z0: Z0[q*8+c][col] = Wi.x + (bi - vb_cum) ----------------
__global__ __launch_bounds__(256) void k_z0(const float* __restrict__ x,
                                            const float* __restrict__ Wi,
                                            const float* __restrict__ bi,
                                            float* ws) {
    int tile = blockIdx.x;   // 0..7 (250 t each)
    int b    = blockIdx.y;   // 0..15
    int qg   = blockIdx.z;   // 0..1
    int tid  = threadIdx.x;
    if (tid >= 250) return;
    int t   = tile * 250 + tid;
    int col = b * T_ + t;
    const float*  xp = x + (size_t)b * D_ * T_ + t;
    const float4* w4 = (const float4*)(Wi + qg * 4 * CD_ * D_);   // 32 rows x 128 float4

    float  chk[32];
    double tot[32];
    #pragma unroll
    for (int i = 0; i < 32; ++i) tot[i] = 0.0;

    for (int ch = 0; ch < 8; ++ch) {
        #pragma unroll
        for (int i = 0; i < 32; ++i) chk[i] = 0.0f;
        #pragma unroll
        for (int d4i = 0; d4i < 16; ++d4i) {
            int d4 = ch * 16 + d4i;
            int d  = d4 * 4;
            float x0 = xp[(size_t)(d + 0) * T_];
            float x1 = xp[(size_t)(d + 1) * T_];
            float x2 = xp[(size_t)(d + 2) * T_];
            float x3 = xp[(size_t)(d + 3) * T_];
            #pragma unroll
            for (int qc = 0; qc < 32; ++qc) {
                float4 w = w4[qc * 128 + d4];
                chk[qc] = fmaf(w.x, x0, fmaf(w.y, x1, fmaf(w.z, x2, fmaf(w.w, x3, chk[qc]))));
            }
        }
        #pragma unroll
        for (int i = 0; i < 32; ++i) tot[i] += (double)chk[i];
    }

    #pragma unroll
    for (int qc = 0; qc < 32; ++qc) {
        int row = qg * 32 + qc;      // q*8+c
        int q = row >> 3, c = row & 7;
        float bias = bi[q * CD_ + c];
        for (int p = 0; p < q; ++p) bias -= ws[WS_VBP + (q * 8 + p) * 8 + c];
        ws[WS_Z0 + (size_t)row * NCOL + col] = (float)tot[qc] + bias;
    }
}

// ---------------- K_vq: per-column 8-stage VQ (argmax + history in regs) ----------------
__global__ __launch_bounds__(128) void k_vq(const float* __restrict__ cb,
                                            float* ws, float* __restrict__ out) {
    __shared__ float4 s_cb4[CS_ * 2];   // 32KB raw codebook
    __shared__ float  s_inv[CS_];       // 4KB inverse norms
    float* s_cb = (float*)s_cb4;

    int tid  = threadIdx.x;
    int blk  = blockIdx.x;
    int half = tid & 1;
    int col  = blk * 64 + (tid >> 1);
    int lane = tid & 63;
    int wid  = tid >> 6;

    const float* z0 = ws + WS_Z0;
    const float* M  = ws + WS_M;

    float zqh[Q_][CD_];
    float lossv[Q_];

    #pragma unroll
    for (int q = 0; q < Q_; ++q) {
        __syncthreads();
        // stage codebook -> LDS, inv norms on the fly
        const float4* src = (const float4*)(cb + q * CS_ * CD_);
        #pragma unroll
        for (int j = 0; j < 16; ++j) {
            int f = j * 128 + tid;
            float4 v = src[f];
            s_cb4[f] = v;
            float ss = v.x * v.x + v.y * v.y + v.z * v.z + v.w * v.w;
            float so = __shfl_down(ss, 1);
            if ((tid & 1) == 0) {
                float nrm = sqrtf(ss + so);
                s_inv[f >> 1] = 1.0f / fmaxf(nrm, 1e-12f);
            }
        }
        __syncthreads();

        // z_e = Z0 - corrections from history
        float ze[CD_];
        #pragma unroll
        for (int c = 0; c < CD_; ++c) ze[c] = z0[(q * 8 + c) * NCOL + col];
        #pragma unroll
        for (int p = 0; p < q; ++p) {
            const float4* Mp = (const float4*)(M + (q * 8 + p) * 64);
            #pragma unroll
            for (int c = 0; c < CD_; ++c) {
                float4 a = Mp[c * 2 + 0];
                float4 bq = Mp[c * 2 + 1];
                float tc = a.x * zqh[p][0];
                tc = fmaf(a.y,  zqh[p][1], tc);
                tc = fmaf(a.z,  zqh[p][2], tc);
                tc = fmaf(a.w,  zqh[p][3], tc);
                tc = fmaf(bq.x, zqh[p][4], tc);
                tc = fmaf(bq.y, zqh[p][5], tc);
                tc = fmaf(bq.z, zqh[p][6], tc);
                tc = fmaf(bq.w, zqh[p][7], tc);
                ze[c] -= tc;
            }
        }

        // argmax over this lane's 512 codes, 4 independent chains
        const float4* cb4 = (const float4*)s_cb;
        int base = half * 512;
        float b0 = -1e30f, b1 = -1e30f, b2 = -1e30f, b3 = -1e30f;
        int   n0 = 0, n1 = 0, n2 = 0, n3 = 0;
        for (int n = base; n < base + 512; n += 4) {
            float4 va0 = cb4[(n + 0) * 2], vb0 = cb4[(n + 0) * 2 + 1];
            float4 va1 = cb4[(n + 1) * 2], vb1 = cb4[(n + 1) * 2 + 1];
            float4 va2 = cb4[(n + 2) * 2], vb2 = cb4[(n + 2) * 2 + 1];
            float4 va3 = cb4[(n + 3) * 2], vb3 = cb4[(n + 3) * 2 + 1];
            float s0 = ze[0] * va0.x; s0 = fmaf(ze[1], va0.y, s0); s0 = fmaf(ze[2], va0.z, s0); s0 = fmaf(ze[3], va0.w, s0);
            s0 = fmaf(ze[4], vb0.x, s0); s0 = fmaf(ze[5], vb0.y, s0); s0 = fmaf(ze[6], vb0.z, s0); s0 = fmaf(ze[7], vb0.w, s0);
            float s1 = ze[0] * va1.x; s1 = fmaf(ze[1], va1.y, s1); s1 = fmaf(ze[2], va1.z, s1); s1 = fmaf(ze[3], va1.w, s1);
            s1 = fmaf(ze[4], vb1.x, s1); s1 = fmaf(ze[5], vb1.y, s1); s1 = fmaf(ze[6], vb1.z, s1); s1 = fmaf(ze[7], vb1.w, s1);
            float s2 = ze[0] * va2.x; s2 = fmaf(ze[1], va2.y, s2); s2 = fmaf(ze[2], va2.z, s2); s2 = fmaf(ze[3], va2.w, s2);
            s2 = fmaf(ze[4], vb2.x, s2); s2 = fmaf(ze[5], vb2.y, s2); s2 = fmaf(ze[6], vb2.z, s2); s2 = fmaf(ze[7], vb2.w, s2);
            float s3 = ze[0] * va3.x; s3 = fmaf(ze[1], va3.y, s3); s3 = fmaf(ze[2], va3.z, s3); s3 = fmaf(ze[3], va3.w, s3);
            s3 = fmaf(ze[4], vb3.x, s3); s3 = fmaf(ze[5], vb3.y, s3); s3 = fmaf(ze[6], vb3.z, s3); s3 = fmaf(ze[7], vb3.w, s3);
            s0 *= s_inv[n + 0];
            s1 *= s_inv[n + 1];
            s2 *= s_inv[n + 2];
            s3 *= s_inv[n + 3];
            if (s0 > b0) { b0 = s0; n0 = n + 0; }
            if (s1 > b1) { b1 = s1; n1 = n + 1; }
            if (s2 > b2) { b2 = s2; n2 = n + 2; }
            if (s3 > b3) { b3 = s3; n3 = n + 3; }
        }
        // merge chains (prefer lowest index on ties = argmax first-occurrence)
        float bb = b0; int nn = n0;
        if (b1 > bb || (b1 == bb && n1 < nn)) { bb = b1; nn = n1; }
        if (b2 > bb || (b2 == bb && n2 < nn)) { bb = b2; nn = n2; }
        if (b3 > bb || (b3 == bb && n3 < nn)) { bb = b3; nn = n3; }
        // merge the two lanes of this column
        float ob = __shfl_xor(bb, 1);
        int   on = __shfl_xor(nn, 1);
        if (ob > bb || (ob == bb && on < nn)) { bb = ob; nn = on; }

        // zq lookup (raw codebook), update history
        const float* zrow = s_cb + nn * CD_;
        float zq[CD_];
        #pragma unroll
        for (int c = 0; c < CD_; ++c) { zq[c] = zrow[c]; zqh[q][c] = zq[c]; }

        if (half == 0) {
            out[OFF_IDX + q * NCOL + col] = (float)nn;
            float l = 0.0f;
            #pragma unroll
            for (int c = 0; c < CD_; ++c) { float dd = ze[c] - zq[c]; l = fmaf(dd, dd, l); }
            lossv[q] = l;
            #pragma unroll
            for (int c = 0; c < CD_; ++c) ws[WS_ZQ + (q * 8 + c) * NCOL + col] = zq[c];
        } else {
            lossv[q] = 0.0f;
        }
    }

    // per-wave loss partials (deterministic, no atomics)
    #pragma unroll
    for (int q = 0; q < Q_; ++q) {
        float l = lossv[q];
        l += __shfl_xor(l, 1);
        l += __shfl_xor(l, 2);
        l += __shfl_xor(l, 4);
        l += __shfl_xor(l, 8);
        l += __shfl_xor(l, 16);
        l += __shfl_xor(l, 32);
        if (lane == 0) ws[WS_LP + (q * 500 + blk) * 2 + wid] = l;
    }
}

// ---------------- K_out: q = Wo.zq + bo, all_q + quantized_out writes ----------------
__global__ __launch_bounds__(128) void k_out(const float* __restrict__ Wo,
                                             const float* __restrict__ bo,
                                             const float* __restrict__ ws,
                                             float* __restrict__ out) {
    __shared__ float4 s_wo4[Q_ * 128 * 2];  // [q][dd][c] 32KB
    __shared__ float  s_bo[Q_ * 128];       // 4KB
    float* s_wo = (float*)s_wo4;

    int tid  = threadIdx.x;
    int tile = blockIdx.x;   // 0..15 (125 t each)
    int b    = blockIdx.y;   // 0..15
    int t    = tile * 125 + tid;
    bool act = tid < 125;
    int col  = b * T_ + t;

    float zq[Q_][CD_];
    if (act) {
        #pragma unroll
        for (int q = 0; q < Q_; ++q)
            #pragma unroll
            for (int c = 0; c < CD_; ++c)
                zq[q][c] = ws[WS_ZQ + (q * 8 + c) * NCOL + col];
    }

    for (int chunk = 0; chunk < 4; ++chunk) {
        int d0 = chunk * 128;
        __syncthreads();
        #pragma unroll
        for (int j = 0; j < 16; ++j) {           // 2048 float4 of Wo chunk
            int f = j * 128 + tid;
            int q = f >> 8;                       // 256 float4 per q
            int r = f & 255;
            s_wo4[f] = ((const float4*)(Wo + q * D_ * CD_ + d0 * CD_))[r];
        }
        #pragma unroll
        for (int j = 0; j < 8; ++j) {            // 1024 floats of bo chunk
            int f = j * 128 + tid;
            int q = f >> 7, dd = f & 127;
            s_bo[f] = bo[q * D_ + d0 + dd];
        }
        __syncthreads();

        if (act) {
            for (int dd = 0; dd < 128; ++dd) {
                int d = d0 + dd;
                float qsum = 0.0f;
                size_t obase = (size_t)OFF_ALLQ + ((size_t)b * D_ + d) * T_ + t;
                #pragma unroll
                for (int q = 0; q < Q_; ++q) {
                    const float4* wr = (const float4*)(s_wo + (q * 128 + dd) * 8);
                    float4 w0 = wr[0], w1 = wr[1];
                    float qv = s_bo[q * 128 + dd];
                    qv = fmaf(w0.x, zq[q][0], qv);
                    qv = fmaf(w0.y, zq[q][1], qv);
                    qv = fmaf(w0.z, zq[q][2], qv);
                    qv = fmaf(w0.w, zq[q][3], qv);
                    qv = fmaf(w1.x, zq[q][4], qv);
                    qv = fmaf(w1.y, zq[q][5], qv);
                    qv = fmaf(w1.z, zq[q][6], qv);
                    qv = fmaf(w1.w, zq[q][7], qv);
                    out[obase + (size_t)q * (B_ * D_ * T_)] = qv;
                    qsum += qv;
                }
                out[OFF_QOUT + ((size_t)b * D_ + d) * T_ + t] = qsum;
            }
        }
    }
}

// ---------------- K_loss: finalize 8 losses from per-wave partials ----------------
__global__ void k_loss(const float* __restrict__ ws, float* __restrict__ out) {
    int tid = threadIdx.x;        // 256
    int q = tid >> 5, i = tid & 31;
    double s = 0.0;
    for (int j = i; j < 1000; j += 32) s += (double)ws[WS_LP + q * 1000 + j];
    s += __shfl_xor(s, 1);
    s += __shfl_xor(s, 2);
    s += __shfl_xor(s, 4);
    s += __shfl_xor(s, 8);
    s += __shfl_xor(s, 16);
    if (i == 0) out[OFF_LOSS + q] = (float)(1.25 * s / 256000.0);
}

extern "C" void kernel_launch(void* const* d_in, const int* in_sizes, int n_in,
                              void* d_out, int out_size, void* d_ws, size_t ws_size,
                              hipStream_t stream) {
    const float* x  = (const float*)d_in[0];
    const float* Wi = (const float*)d_in[1];
    const float* bi = (const float*)d_in[2];
    const float* Wo = (const float*)d_in[3];
    const float* bo = (const float*)d_in[4];
    const float* cb = (const float*)d_in[5];
    float* out = (float*)d_out;
    float* ws  = (float*)d_ws;

    hipLaunchKernelGGL(k_precompute_M,   dim3(64),       dim3(64),  0, stream, Wi, Wo, ws);
    hipLaunchKernelGGL(k_precompute_vbp, dim3(64),       dim3(64),  0, stream, Wi, bo, ws);
    hipLaunchKernelGGL(k_z0,             dim3(8, 16, 2), dim3(256), 0, stream, x, Wi, bi, ws);
    hipLaunchKernelGGL(k_vq,             dim3(500),      dim3(128), 0, stream, cb, ws, out);
    hipLaunchKernelGGL(k_out,            dim3(16, 16),   dim3(128), 0, stream, Wo, bo, ws, out);
    hipLaunchKernelGGL(k_loss,           dim3(1),        dim3(256), 0, stream, ws, out);
}

// Round 2
// 816.475 us; speedup vs baseline: 1.3135x; 1.3135x over previous
//
#include <hip/hip_runtime.h>

#define B_   16
#define D_   512
#define T_   2000
#define Q_   8
#define CD_  8
#define CS_  1024
#define NCOL 32000   // B_*T_

// workspace float offsets
#define WS_Z0   0              // 64*32000 = 2048000
#define WS_ZQ   2048000        // 64*32000 = 2048000
#define WS_M    4096000        // 64*64    = 4096
#define WS_VBP  4100096        // 8*8*8    = 512
#define WS_LP   4100608        // 8*500*2  = 8000

// d_out float offsets (quantized_out, all_idx, all_loss, all_q)
#define OFF_QOUT 0
#define OFF_IDX  16384000
#define OFF_LOSS 16640000
#define OFF_ALLQ 16640008

// ---------------- K_M: M[q][p][c][c'] = sum_d Wi[q,c,d] * Wo[p,d,c'] ----------------
__global__ void k_precompute_M(const float* __restrict__ Wi, const float* __restrict__ Wo,
                               float* __restrict__ ws) {
    int q = blockIdx.x >> 3, p = blockIdx.x & 7;
    int c = threadIdx.x >> 3, cp = threadIdx.x & 7;
    const float* wir = Wi + (q * CD_ + c) * D_;
    const float* wop = Wo + p * (D_ * CD_) + cp;
    double acc = 0.0;
    #pragma unroll 4
    for (int d = 0; d < D_; ++d) acc += (double)wir[d] * (double)wop[d * CD_];
    ws[WS_M + (q * 8 + p) * 64 + c * 8 + cp] = (float)acc;
}

// ---------------- K_vbp: vbp[q][p][c] = sum_d Wi[q,c,d] * bo[p,d] ----------------
__global__ void k_precompute_vbp(const float* __restrict__ Wi, const float* __restrict__ bo,
                                 float* __restrict__ ws) {
    int q = blockIdx.x >> 3, p = blockIdx.x & 7;
    int c = threadIdx.x >> 3, ds = threadIdx.x & 7;
    double a = 0.0;
    if (p < q) {
        const float* wir = Wi + (q * CD_ + c) * D_;
        const float* bop = bo + p * D_;
        for (int d = ds; d < D_; d += 8) a += (double)wir[d] * (double)bop[d];
    }
    a += __shfl_xor(a, 1);
    a += __shfl_xor(a, 2);
    a += __shfl_xor(a, 4);
    if (ds == 0) ws[WS_VBP + (q * 8 + p) * 8 + c] = (float)a;
}

// ---------------- K_z0: Z0[row][col] = Wi.x + (bi - vb_cum), 16 rows/thread ----------------
// grid (125, 4), block 256. col = blockIdx.x*256+tid; rows rg*16..rg*16+15.
// W accesses are wave-uniform -> s_load via scalar cache; x loads coalesced 4B/lane.
__global__ __launch_bounds__(256) void k_z0(const float* __restrict__ x,
                                            const float* __restrict__ Wi,
                                            const float* __restrict__ bi,
                                            float* ws) {
    int col = blockIdx.x * 256 + threadIdx.x;   // 125*256 = 32000, exact
    int rg  = blockIdx.y;                       // 0..3
    int b = col / T_;
    int t = col - b * T_;
    const float* xp = x + (size_t)b * (D_ * T_) + t;
    const float* Wr = Wi + rg * 16 * D_;        // uniform base

    double tot[16];
    #pragma unroll
    for (int r = 0; r < 16; ++r) tot[r] = 0.0;

    for (int ch = 0; ch < 8; ++ch) {
        float chk[16];
        #pragma unroll
        for (int r = 0; r < 16; ++r) chk[r] = 0.0f;
        #pragma unroll
        for (int k4 = 0; k4 < 16; ++k4) {
            int d = ch * 64 + k4 * 4;
            float x0 = xp[(size_t)(d + 0) * T_];
            float x1 = xp[(size_t)(d + 1) * T_];
            float x2 = xp[(size_t)(d + 2) * T_];
            float x3 = xp[(size_t)(d + 3) * T_];
            #pragma unroll
            for (int r = 0; r < 16; ++r) {
                const float* w = Wr + r * D_ + d;   // uniform -> SGPR
                chk[r] = fmaf(w[0], x0, fmaf(w[1], x1, fmaf(w[2], x2, fmaf(w[3], x3, chk[r]))));
            }
        }
        #pragma unroll
        for (int r = 0; r < 16; ++r) tot[r] += (double)chk[r];
    }

    #pragma unroll
    for (int r = 0; r < 16; ++r) {
        int row = rg * 16 + r;       // q*8+c
        int q = row >> 3, c = row & 7;
        float bias = bi[row];
        for (int p = 0; p < q; ++p) bias -= ws[WS_VBP + (q * 8 + p) * 8 + c];
        ws[WS_Z0 + (size_t)row * NCOL + col] = (float)tot[r] + bias;
    }
}

// ---------------- K_vq: per-column 8-stage VQ (argmax + history in regs) ----------------
__global__ __launch_bounds__(128) void k_vq(const float* __restrict__ cb,
                                            float* ws, float* __restrict__ out) {
    __shared__ float4 s_cb4[CS_ * 2];   // 32KB raw codebook
    __shared__ float  s_inv[CS_];       // 4KB inverse norms
    float* s_cb = (float*)s_cb4;

    int tid  = threadIdx.x;
    int blk  = blockIdx.x;
    int half = tid & 1;
    int col  = blk * 64 + (tid >> 1);
    int lane = tid & 63;
    int wid  = tid >> 6;

    const float* z0 = ws + WS_Z0;
    const float* M  = ws + WS_M;

    float zqh[Q_][CD_];
    float lossv[Q_];

    #pragma unroll
    for (int q = 0; q < Q_; ++q) {
        __syncthreads();
        // stage codebook -> LDS, inv norms on the fly
        const float4* src = (const float4*)(cb + q * CS_ * CD_);
        #pragma unroll
        for (int j = 0; j < 16; ++j) {
            int f = j * 128 + tid;
            float4 v = src[f];
            s_cb4[f] = v;
            float ss = v.x * v.x + v.y * v.y + v.z * v.z + v.w * v.w;
            float so = __shfl_down(ss, 1);
            if ((tid & 1) == 0) {
                float nrm = sqrtf(ss + so);
                s_inv[f >> 1] = 1.0f / fmaxf(nrm, 1e-12f);
            }
        }
        __syncthreads();

        // z_e = Z0 - corrections from history
        float ze[CD_];
        #pragma unroll
        for (int c = 0; c < CD_; ++c) ze[c] = z0[(q * 8 + c) * NCOL + col];
        #pragma unroll
        for (int p = 0; p < q; ++p) {
            const float4* Mp = (const float4*)(M + (q * 8 + p) * 64);
            #pragma unroll
            for (int c = 0; c < CD_; ++c) {
                float4 a = Mp[c * 2 + 0];
                float4 bq = Mp[c * 2 + 1];
                float tc = a.x * zqh[p][0];
                tc = fmaf(a.y,  zqh[p][1], tc);
                tc = fmaf(a.z,  zqh[p][2], tc);
                tc = fmaf(a.w,  zqh[p][3], tc);
                tc = fmaf(bq.x, zqh[p][4], tc);
                tc = fmaf(bq.y, zqh[p][5], tc);
                tc = fmaf(bq.z, zqh[p][6], tc);
                tc = fmaf(bq.w, zqh[p][7], tc);
                ze[c] -= tc;
            }
        }

        // argmax over this lane's 512 codes, 4 independent chains
        const float4* cb4 = (const float4*)s_cb;
        int base = half * 512;
        float b0 = -1e30f, b1 = -1e30f, b2 = -1e30f, b3 = -1e30f;
        int   n0 = 0, n1 = 0, n2 = 0, n3 = 0;
        for (int n = base; n < base + 512; n += 4) {
            float4 va0 = cb4[(n + 0) * 2], vb0 = cb4[(n + 0) * 2 + 1];
            float4 va1 = cb4[(n + 1) * 2], vb1 = cb4[(n + 1) * 2 + 1];
            float4 va2 = cb4[(n + 2) * 2], vb2 = cb4[(n + 2) * 2 + 1];
            float4 va3 = cb4[(n + 3) * 2], vb3 = cb4[(n + 3) * 2 + 1];
            float s0 = ze[0] * va0.x; s0 = fmaf(ze[1], va0.y, s0); s0 = fmaf(ze[2], va0.z, s0); s0 = fmaf(ze[3], va0.w, s0);
            s0 = fmaf(ze[4], vb0.x, s0); s0 = fmaf(ze[5], vb0.y, s0); s0 = fmaf(ze[6], vb0.z, s0); s0 = fmaf(ze[7], vb0.w, s0);
            float s1 = ze[0] * va1.x; s1 = fmaf(ze[1], va1.y, s1); s1 = fmaf(ze[2], va1.z, s1); s1 = fmaf(ze[3], va1.w, s1);
            s1 = fmaf(ze[4], vb1.x, s1); s1 = fmaf(ze[5], vb1.y, s1); s1 = fmaf(ze[6], vb1.z, s1); s1 = fmaf(ze[7], vb1.w, s1);
            float s2 = ze[0] * va2.x; s2 = fmaf(ze[1], va2.y, s2); s2 = fmaf(ze[2], va2.z, s2); s2 = fmaf(ze[3], va2.w, s2);
            s2 = fmaf(ze[4], vb2.x, s2); s2 = fmaf(ze[5], vb2.y, s2); s2 = fmaf(ze[6], vb2.z, s2); s2 = fmaf(ze[7], vb2.w, s2);
            float s3 = ze[0] * va3.x; s3 = fmaf(ze[1], va3.y, s3); s3 = fmaf(ze[2], va3.z, s3); s3 = fmaf(ze[3], va3.w, s3);
            s3 = fmaf(ze[4], vb3.x, s3); s3 = fmaf(ze[5], vb3.y, s3); s3 = fmaf(ze[6], vb3.z, s3); s3 = fmaf(ze[7], vb3.w, s3);
            s0 *= s_inv[n + 0];
            s1 *= s_inv[n + 1];
            s2 *= s_inv[n + 2];
            s3 *= s_inv[n + 3];
            if (s0 > b0) { b0 = s0; n0 = n + 0; }
            if (s1 > b1) { b1 = s1; n1 = n + 1; }
            if (s2 > b2) { b2 = s2; n2 = n + 2; }
            if (s3 > b3) { b3 = s3; n3 = n + 3; }
        }
        // merge chains (prefer lowest index on ties = argmax first-occurrence)
        float bb = b0; int nn = n0;
        if (b1 > bb || (b1 == bb && n1 < nn)) { bb = b1; nn = n1; }
        if (b2 > bb || (b2 == bb && n2 < nn)) { bb = b2; nn = n2; }
        if (b3 > bb || (b3 == bb && n3 < nn)) { bb = b3; nn = n3; }
        // merge the two lanes of this column
        float ob = __shfl_xor(bb, 1);
        int   on = __shfl_xor(nn, 1);
        if (ob > bb || (ob == bb && on < nn)) { bb = ob; nn = on; }

        // zq lookup (raw codebook), update history
        const float* zrow = s_cb + nn * CD_;
        float zq[CD_];
        #pragma unroll
        for (int c = 0; c < CD_; ++c) { zq[c] = zrow[c]; zqh[q][c] = zq[c]; }

        if (half == 0) {
            out[OFF_IDX + q * NCOL + col] = (float)nn;
            float l = 0.0f;
            #pragma unroll
            for (int c = 0; c < CD_; ++c) { float dd = ze[c] - zq[c]; l = fmaf(dd, dd, l); }
            lossv[q] = l;
            #pragma unroll
            for (int c = 0; c < CD_; ++c) ws[WS_ZQ + (q * 8 + c) * NCOL + col] = zq[c];
        } else {
            lossv[q] = 0.0f;
        }
    }

    // per-wave loss partials (deterministic, no atomics)
    #pragma unroll
    for (int q = 0; q < Q_; ++q) {
        float l = lossv[q];
        l += __shfl_xor(l, 1);
        l += __shfl_xor(l, 2);
        l += __shfl_xor(l, 4);
        l += __shfl_xor(l, 8);
        l += __shfl_xor(l, 16);
        l += __shfl_xor(l, 32);
        if (lane == 0) ws[WS_LP + (q * 500 + blk) * 2 + wid] = l;
    }
}

// ---------------- K_out: q = Wo.zq + bo, all_q + quantized_out writes ----------------
// grid (16, 16, 4): t-tile, b, d-chunk. 1024 blocks for store queue depth.
__global__ __launch_bounds__(128) void k_out(const float* __restrict__ Wo,
                                             const float* __restrict__ bo,
                                             const float* __restrict__ ws,
                                             float* __restrict__ out) {
    __shared__ float4 s_wo4[Q_ * 128 * 2];  // [q][dd][c] 32KB (this d-chunk)
    __shared__ float  s_bo[Q_ * 128];       // 4KB
    float* s_wo = (float*)s_wo4;

    int tid  = threadIdx.x;
    int tile = blockIdx.x;   // 0..15 (125 t each)
    int b    = blockIdx.y;   // 0..15
    int d0   = blockIdx.z * 128;  // 0..3
    int t    = tile * 125 + tid;
    bool act = tid < 125;
    int col  = b * T_ + t;

    #pragma unroll
    for (int j = 0; j < 16; ++j) {           // 2048 float4 of Wo chunk
        int f = j * 128 + tid;
        int q = f >> 8;                       // 256 float4 per q
        int r = f & 255;
        s_wo4[f] = ((const float4*)(Wo + q * D_ * CD_ + d0 * CD_))[r];
    }
    #pragma unroll
    for (int j = 0; j < 8; ++j) {            // 1024 floats of bo chunk
        int f = j * 128 + tid;
        int q = f >> 7, dd = f & 127;
        s_bo[f] = bo[q * D_ + d0 + dd];
    }
    __syncthreads();

    float zq[Q_][CD_];
    if (act) {
        #pragma unroll
        for (int q = 0; q < Q_; ++q)
            #pragma unroll
            for (int c = 0; c < CD_; ++c)
                zq[q][c] = ws[WS_ZQ + (q * 8 + c) * NCOL + col];

        for (int dd = 0; dd < 128; ++dd) {
            int d = d0 + dd;
            float qsum = 0.0f;
            size_t obase = (size_t)OFF_ALLQ + ((size_t)b * D_ + d) * T_ + t;
            #pragma unroll
            for (int q = 0; q < Q_; ++q) {
                const float4* wr = (const float4*)(s_wo + (q * 128 + dd) * 8);
                float4 w0 = wr[0], w1 = wr[1];
                float qv = s_bo[q * 128 + dd];
                qv = fmaf(w0.x, zq[q][0], qv);
                qv = fmaf(w0.y, zq[q][1], qv);
                qv = fmaf(w0.z, zq[q][2], qv);
                qv = fmaf(w0.w, zq[q][3], qv);
                qv = fmaf(w1.x, zq[q][4], qv);
                qv = fmaf(w1.y, zq[q][5], qv);
                qv = fmaf(w1.z, zq[q][6], qv);
                qv = fmaf(w1.w, zq[q][7], qv);
                out[obase + (size_t)q * (B_ * D_ * T_)] = qv;
                qsum += qv;
            }
            out[OFF_QOUT + ((size_t)b * D_ + d) * T_ + t] = qsum;
        }
    }
}

// ---------------- K_loss: finalize 8 losses from per-wave partials ----------------
__global__ void k_loss(const float* __restrict__ ws, float* __restrict__ out) {
    int tid = threadIdx.x;        // 256
    int q = tid >> 5, i = tid & 31;
    double s = 0.0;
    for (int j = i; j < 1000; j += 32) s += (double)ws[WS_LP + q * 1000 + j];
    s += __shfl_xor(s, 1);
    s += __shfl_xor(s, 2);
    s += __shfl_xor(s, 4);
    s += __shfl_xor(s, 8);
    s += __shfl_xor(s, 16);
    if (i == 0) out[OFF_LOSS + q] = (float)(1.25 * s / 256000.0);
}

extern "C" void kernel_launch(void* const* d_in, const int* in_sizes, int n_in,
                              void* d_out, int out_size, void* d_ws, size_t ws_size,
                              hipStream_t stream) {
    const float* x  = (const float*)d_in[0];
    const float* Wi = (const float*)d_in[1];
    const float* bi = (const float*)d_in[2];
    const float* Wo = (const float*)d_in[3];
    const float* bo = (const float*)d_in[4];
    const float* cb = (const float*)d_in[5];
    float* out = (float*)d_out;
    float* ws  = (float*)d_ws;

    hipLaunchKernelGGL(k_precompute_M,   dim3(64),        dim3(64),  0, stream, Wi, Wo, ws);
    hipLaunchKernelGGL(k_precompute_vbp, dim3(64),        dim3(64),  0, stream, Wi, bo, ws);
    hipLaunchKernelGGL(k_z0,             dim3(125, 4),    dim3(256), 0, stream, x, Wi, bi, ws);
    hipLaunchKernelGGL(k_vq,             dim3(500),       dim3(128), 0, stream, cb, ws, out);
    hipLaunchKernelGGL(k_out,            dim3(16, 16, 4), dim3(128), 0, stream, Wo, bo, ws, out);
    hipLaunchKernelGGL(k_loss,           dim3(1),         dim3(256), 0, stream, ws, out);
}

// Round 3
// 814.162 us; speedup vs baseline: 1.3172x; 1.0028x over previous
//
#include <hip/hip_runtime.h>

#define B_   16
#define D_   512
#define T_   2000
#define Q_   8
#define CD_  8
#define CS_  1024
#define NCOL 32000   // B_*T_

// workspace float offsets
#define WS_Z0   0              // 64*32000 = 2048000
#define WS_ZQ   2048000        // 64*32000 = 2048000
#define WS_M    4096000        // 64*64    = 4096
#define WS_VBP  4100096        // 8*8*8    = 512
#define WS_LP   4100608        // 8*500    = 4000
#define WS_INV  4108608        // 8*1024   = 8192

// d_out float offsets (quantized_out, all_idx, all_loss, all_q)
#define OFF_QOUT 0
#define OFF_IDX  16384000
#define OFF_LOSS 16640000
#define OFF_ALLQ 16640008

// ---------------- K_M: M[q][p][c][c'] = sum_d Wi[q,c,d] * Wo[p,d,c'] ----------------
__global__ void k_precompute_M(const float* __restrict__ Wi, const float* __restrict__ Wo,
                               float* __restrict__ ws) {
    int q = blockIdx.x >> 3, p = blockIdx.x & 7;
    int c = threadIdx.x >> 3, cp = threadIdx.x & 7;
    const float* wir = Wi + (q * CD_ + c) * D_;
    const float* wop = Wo + p * (D_ * CD_) + cp;
    double acc = 0.0;
    #pragma unroll 4
    for (int d = 0; d < D_; ++d) acc += (double)wir[d] * (double)wop[d * CD_];
    ws[WS_M + (q * 8 + p) * 64 + c * 8 + cp] = (float)acc;
}

// ---------------- K_vbp: vbp[q][p][c] = sum_d Wi[q,c,d] * bo[p,d] ----------------
__global__ void k_precompute_vbp(const float* __restrict__ Wi, const float* __restrict__ bo,
                                 float* __restrict__ ws) {
    int q = blockIdx.x >> 3, p = blockIdx.x & 7;
    int c = threadIdx.x >> 3, ds = threadIdx.x & 7;
    double a = 0.0;
    if (p < q) {
        const float* wir = Wi + (q * CD_ + c) * D_;
        const float* bop = bo + p * D_;
        for (int d = ds; d < D_; d += 8) a += (double)wir[d] * (double)bop[d];
    }
    a += __shfl_xor(a, 1);
    a += __shfl_xor(a, 2);
    a += __shfl_xor(a, 4);
    if (ds == 0) ws[WS_VBP + (q * 8 + p) * 8 + c] = (float)a;
}

// ---------------- K_norm: inverse codebook norms (same float expr as before) ----------------
__global__ void k_norm(const float* __restrict__ cb, float* __restrict__ ws) {
    int id = blockIdx.x * 256 + threadIdx.x;   // 32 blocks -> 8192
    const float4* r = (const float4*)(cb + (size_t)id * CD_);
    float4 v = r[0], w = r[1];
    float ss = v.x * v.x + v.y * v.y + v.z * v.z + v.w * v.w;
    float so = w.x * w.x + w.y * w.y + w.z * w.z + w.w * w.w;
    float nrm = sqrtf(ss + so);
    ws[WS_INV + id] = 1.0f / fmaxf(nrm, 1e-12f);
}

// ---------------- K_z0: Z0[row][col] = Wi.x + (bi - vb_cum), 16 rows/thread ----------------
__global__ __launch_bounds__(256) void k_z0(const float* __restrict__ x,
                                            const float* __restrict__ Wi,
                                            const float* __restrict__ bi,
                                            float* ws) {
    int col = blockIdx.x * 256 + threadIdx.x;   // 125*256 = 32000, exact
    int rg  = blockIdx.y;                       // 0..3
    int b = col / T_;
    int t = col - b * T_;
    const float* xp = x + (size_t)b * (D_ * T_) + t;
    const float* Wr = Wi + rg * 16 * D_;        // uniform base

    double tot[16];
    #pragma unroll
    for (int r = 0; r < 16; ++r) tot[r] = 0.0;

    for (int ch = 0; ch < 8; ++ch) {
        float chk[16];
        #pragma unroll
        for (int r = 0; r < 16; ++r) chk[r] = 0.0f;
        #pragma unroll
        for (int k4 = 0; k4 < 16; ++k4) {
            int d = ch * 64 + k4 * 4;
            float x0 = xp[(size_t)(d + 0) * T_];
            float x1 = xp[(size_t)(d + 1) * T_];
            float x2 = xp[(size_t)(d + 2) * T_];
            float x3 = xp[(size_t)(d + 3) * T_];
            #pragma unroll
            for (int r = 0; r < 16; ++r) {
                const float* w = Wr + r * D_ + d;   // uniform -> SGPR
                chk[r] = fmaf(w[0], x0, fmaf(w[1], x1, fmaf(w[2], x2, fmaf(w[3], x3, chk[r]))));
            }
        }
        #pragma unroll
        for (int r = 0; r < 16; ++r) tot[r] += (double)chk[r];
    }

    #pragma unroll
    for (int r = 0; r < 16; ++r) {
        int row = rg * 16 + r;       // q*8+c
        int q = row >> 3, c = row & 7;
        float bias = bi[row];
        for (int p = 0; p < q; ++p) bias -= ws[WS_VBP + (q * 8 + p) * 8 + c];
        ws[WS_Z0 + (size_t)row * NCOL + col] = (float)tot[r] + bias;
    }
}

// ---------------- K_vq: 4 waves/block, SGPR codebook, LDS merge ----------------
// Block owns 64 columns (1/lane). Wave w scans codes [w*256, w*256+256) via
// wave-uniform scalar loads. Partial (best,idx) merged via 2KB LDS; winner's
// code vector gathered from global cb (L2-hot). First-index tie rules kept.
__global__ __launch_bounds__(256) void k_vq(const float* __restrict__ cb,
                                            float* ws, float* __restrict__ out) {
    __shared__ float s_val[4][64];
    __shared__ int   s_idx[4][64];

    int tid  = threadIdx.x;
    int wid  = tid >> 6;
    int lane = tid & 63;
    int blk  = blockIdx.x;
    int col  = blk * 64 + lane;

    const float* z0 = ws + WS_Z0;
    const float* M  = ws + WS_M;

    float zqh[Q_][CD_];
    float lossv[Q_];

    #pragma unroll
    for (int q = 0; q < Q_; ++q) {
        // z_e = Z0 - corrections (computed redundantly in every wave)
        float ze[CD_];
        #pragma unroll
        for (int c = 0; c < CD_; ++c) ze[c] = z0[(q * 8 + c) * NCOL + col];
        #pragma unroll
        for (int p = 0; p < q; ++p) {
            const float4* Mp = (const float4*)(M + (q * 8 + p) * 64);
            #pragma unroll
            for (int c = 0; c < CD_; ++c) {
                float4 a = Mp[c * 2 + 0];
                float4 bq = Mp[c * 2 + 1];
                float tc = a.x * zqh[p][0];
                tc = fmaf(a.y,  zqh[p][1], tc);
                tc = fmaf(a.z,  zqh[p][2], tc);
                tc = fmaf(a.w,  zqh[p][3], tc);
                tc = fmaf(bq.x, zqh[p][4], tc);
                tc = fmaf(bq.y, zqh[p][5], tc);
                tc = fmaf(bq.z, zqh[p][6], tc);
                tc = fmaf(bq.w, zqh[p][7], tc);
                ze[c] -= tc;
            }
        }

        // partial argmax over this wave's 256 codes (uniform scalar loads)
        const float4* cb4 = (const float4*)(cb + ((size_t)q * CS_ + wid * 256) * CD_);
        const float*  iv  = ws + WS_INV + q * CS_ + wid * 256;
        float b0 = -1e30f, b1 = -1e30f, b2 = -1e30f, b3 = -1e30f;
        int   n0 = 0, n1 = 1, n2 = 2, n3 = 3;
        for (int i = 0; i < 256; i += 4) {
            float4 a0 = cb4[(i + 0) * 2], x0 = cb4[(i + 0) * 2 + 1];
            float4 a1 = cb4[(i + 1) * 2], x1 = cb4[(i + 1) * 2 + 1];
            float4 a2 = cb4[(i + 2) * 2], x2 = cb4[(i + 2) * 2 + 1];
            float4 a3 = cb4[(i + 3) * 2], x3 = cb4[(i + 3) * 2 + 1];
            float4 iv4 = *(const float4*)(iv + i);
            float s0 = ze[0] * a0.x; s0 = fmaf(ze[1], a0.y, s0); s0 = fmaf(ze[2], a0.z, s0); s0 = fmaf(ze[3], a0.w, s0);
            s0 = fmaf(ze[4], x0.x, s0); s0 = fmaf(ze[5], x0.y, s0); s0 = fmaf(ze[6], x0.z, s0); s0 = fmaf(ze[7], x0.w, s0);
            float s1 = ze[0] * a1.x; s1 = fmaf(ze[1], a1.y, s1); s1 = fmaf(ze[2], a1.z, s1); s1 = fmaf(ze[3], a1.w, s1);
            s1 = fmaf(ze[4], x1.x, s1); s1 = fmaf(ze[5], x1.y, s1); s1 = fmaf(ze[6], x1.z, s1); s1 = fmaf(ze[7], x1.w, s1);
            float s2 = ze[0] * a2.x; s2 = fmaf(ze[1], a2.y, s2); s2 = fmaf(ze[2], a2.z, s2); s2 = fmaf(ze[3], a2.w, s2);
            s2 = fmaf(ze[4], x2.x, s2); s2 = fmaf(ze[5], x2.y, s2); s2 = fmaf(ze[6], x2.z, s2); s2 = fmaf(ze[7], x2.w, s2);
            float s3 = ze[0] * a3.x; s3 = fmaf(ze[1], a3.y, s3); s3 = fmaf(ze[2], a3.z, s3); s3 = fmaf(ze[3], a3.w, s3);
            s3 = fmaf(ze[4], x3.x, s3); s3 = fmaf(ze[5], x3.y, s3); s3 = fmaf(ze[6], x3.z, s3); s3 = fmaf(ze[7], x3.w, s3);
            s0 *= iv4.x;
            s1 *= iv4.y;
            s2 *= iv4.z;
            s3 *= iv4.w;
            if (s0 > b0) { b0 = s0; n0 = i + 0; }
            if (s1 > b1) { b1 = s1; n1 = i + 1; }
            if (s2 > b2) { b2 = s2; n2 = i + 2; }
            if (s3 > b3) { b3 = s3; n3 = i + 3; }
        }
        // merge 4 chains (tie -> lowest index)
        float bb = b0; int nn = n0;
        if (b1 > bb || (b1 == bb && n1 < nn)) { bb = b1; nn = n1; }
        if (b2 > bb || (b2 == bb && n2 < nn)) { bb = b2; nn = n2; }
        if (b3 > bb || (b3 == bb && n3 < nn)) { bb = b3; nn = n3; }
        nn += wid * 256;

        s_val[wid][lane] = bb;
        s_idx[wid][lane] = nn;
        __syncthreads();

        // cross-wave merge (redundant in all waves). Ranges increase with wid,
        // so strict > keeps the first-max index.
        float gb = s_val[0][lane]; int gn = s_idx[0][lane];
        float t1 = s_val[1][lane]; int m1 = s_idx[1][lane];
        float t2 = s_val[2][lane]; int m2 = s_idx[2][lane];
        float t3 = s_val[3][lane]; int m3 = s_idx[3][lane];
        if (t1 > gb) { gb = t1; gn = m1; }
        if (t2 > gb) { gb = t2; gn = m2; }
        if (t3 > gb) { gb = t3; gn = m3; }
        __syncthreads();

        // gather winner code vector from global (raw codebook)
        const float4* zrow = (const float4*)(cb + ((size_t)q * CS_ + gn) * CD_);
        float4 za = zrow[0], zb = zrow[1];
        zqh[q][0] = za.x; zqh[q][1] = za.y; zqh[q][2] = za.z; zqh[q][3] = za.w;
        zqh[q][4] = zb.x; zqh[q][5] = zb.y; zqh[q][6] = zb.z; zqh[q][7] = zb.w;

        if (wid == 0) {
            out[OFF_IDX + q * NCOL + col] = (float)gn;
            float l = 0.0f;
            #pragma unroll
            for (int c = 0; c < CD_; ++c) { float dd = ze[c] - zqh[q][c]; l = fmaf(dd, dd, l); }
            lossv[q] = l;
            #pragma unroll
            for (int c = 0; c < CD_; ++c) ws[WS_ZQ + (q * 8 + c) * NCOL + col] = zqh[q][c];
        } else {
            lossv[q] = 0.0f;
        }
    }

    // per-block loss partials from wave 0 (deterministic, no atomics)
    if (wid == 0) {
        #pragma unroll
        for (int q = 0; q < Q_; ++q) {
            float l = lossv[q];
            l += __shfl_xor(l, 1);
            l += __shfl_xor(l, 2);
            l += __shfl_xor(l, 4);
            l += __shfl_xor(l, 8);
            l += __shfl_xor(l, 16);
            l += __shfl_xor(l, 32);
            if (lane == 0) ws[WS_LP + q * 500 + blk] = l;
        }
    }
}

// ---------------- K_out: thread = column, Wo/bo via SGPR, no LDS ----------------
// grid (125, 4): col-block, d-chunk. Stores coalesced dword; store-BW bound.
__global__ __launch_bounds__(256) void k_out(const float* __restrict__ Wo,
                                             const float* __restrict__ bo,
                                             const float* __restrict__ ws,
                                             float* __restrict__ out) {
    int col = blockIdx.x * 256 + threadIdx.x;
    int d0  = blockIdx.y * 128;
    int b = col / T_;
    int t = col - b * T_;

    float zq[Q_][CD_];
    #pragma unroll
    for (int q = 0; q < Q_; ++q)
        #pragma unroll
        for (int c = 0; c < CD_; ++c)
            zq[q][c] = ws[WS_ZQ + (q * 8 + c) * NCOL + col];

    size_t cbase = ((size_t)b * D_) * T_ + t;
    for (int dd = 0; dd < 128; ++dd) {
        int d = d0 + dd;
        float qsum = 0.0f;
        size_t dbase = cbase + (size_t)d * T_;
        #pragma unroll
        for (int q = 0; q < Q_; ++q) {
            const float* wr = Wo + (q * D_ + d) * CD_;   // uniform -> scalar loads
            float qv = bo[q * D_ + d];
            qv = fmaf(wr[0], zq[q][0], qv);
            qv = fmaf(wr[1], zq[q][1], qv);
            qv = fmaf(wr[2], zq[q][2], qv);
            qv = fmaf(wr[3], zq[q][3], qv);
            qv = fmaf(wr[4], zq[q][4], qv);
            qv = fmaf(wr[5], zq[q][5], qv);
            qv = fmaf(wr[6], zq[q][6], qv);
            qv = fmaf(wr[7], zq[q][7], qv);
            out[OFF_ALLQ + (size_t)q * (B_ * D_ * T_) + dbase] = qv;
            qsum += qv;
        }
        out[OFF_QOUT + dbase] = qsum;
    }
}

// ---------------- K_loss: finalize 8 losses from per-block partials ----------------
__global__ void k_loss(const float* __restrict__ ws, float* __restrict__ out) {
    int tid = threadIdx.x;        // 256
    int q = tid >> 5, i = tid & 31;
    double s = 0.0;
    for (int j = i; j < 500; j += 32) s += (double)ws[WS_LP + q * 500 + j];
    s += __shfl_xor(s, 1);
    s += __shfl_xor(s, 2);
    s += __shfl_xor(s, 4);
    s += __shfl_xor(s, 8);
    s += __shfl_xor(s, 16);
    if (i == 0) out[OFF_LOSS + q] = (float)(1.25 * s / 256000.0);
}

extern "C" void kernel_launch(void* const* d_in, const int* in_sizes, int n_in,
                              void* d_out, int out_size, void* d_ws, size_t ws_size,
                              hipStream_t stream) {
    const float* x  = (const float*)d_in[0];
    const float* Wi = (const float*)d_in[1];
    const float* bi = (const float*)d_in[2];
    const float* Wo = (const float*)d_in[3];
    const float* bo = (const float*)d_in[4];
    const float* cb = (const float*)d_in[5];
    float* out = (float*)d_out;
    float* ws  = (float*)d_ws;

    hipLaunchKernelGGL(k_precompute_M,   dim3(64),     dim3(64),  0, stream, Wi, Wo, ws);
    hipLaunchKernelGGL(k_precompute_vbp, dim3(64),     dim3(64),  0, stream, Wi, bo, ws);
    hipLaunchKernelGGL(k_norm,           dim3(32),     dim3(256), 0, stream, cb, ws);
    hipLaunchKernelGGL(k_z0,             dim3(125, 4), dim3(256), 0, stream, x, Wi, bi, ws);
    hipLaunchKernelGGL(k_vq,             dim3(500),    dim3(256), 0, stream, cb, ws, out);
    hipLaunchKernelGGL(k_out,            dim3(125, 4), dim3(256), 0, stream, Wo, bo, ws, out);
    hipLaunchKernelGGL(k_loss,           dim3(1),      dim3(256), 0, stream, ws, out);
}

// Round 5
// 796.842 us; speedup vs baseline: 1.3458x; 1.0217x over previous
//
#include <hip/hip_runtime.h>

#define B_   16
#define D_   512
#define T_   2000
#define Q_   8
#define CD_  8
#define CS_  1024
#define NCOL 32000   // B_*T_

// workspace float offsets
#define WS_Z0   0              // 64*32000 = 2048000
#define WS_ZQ   2048000        // 64*32000 = 2048000
#define WS_M    4096000        // 64*64    = 4096
#define WS_VBP  4100096        // 8*8*8    = 512
#define WS_LP   4100608        // 8*500    = 4000
#define WS_INV  4108608        // 8*1024   = 8192

// d_out float offsets (quantized_out, all_idx, all_loss, all_q)
#define OFF_QOUT 0
#define OFF_IDX  16384000
#define OFF_LOSS 16640000
#define OFF_ALLQ 16640008

// ---------------- K_M: M[q][p][c][c'] = sum_d Wi[q,c,d] * Wo[p,d,c'] ----------------
__global__ void k_precompute_M(const float* __restrict__ Wi, const float* __restrict__ Wo,
                               float* __restrict__ ws) {
    int q = blockIdx.x >> 3, p = blockIdx.x & 7;
    int c = threadIdx.x >> 3, cp = threadIdx.x & 7;
    const float* wir = Wi + (q * CD_ + c) * D_;
    const float* wop = Wo + p * (D_ * CD_) + cp;
    double acc = 0.0;
    #pragma unroll 4
    for (int d = 0; d < D_; ++d) acc += (double)wir[d] * (double)wop[d * CD_];
    ws[WS_M + (q * 8 + p) * 64 + c * 8 + cp] = (float)acc;
}

// ---------------- K_vbp: vbp[q][p][c] = sum_d Wi[q,c,d] * bo[p,d] ----------------
__global__ void k_precompute_vbp(const float* __restrict__ Wi, const float* __restrict__ bo,
                                 float* __restrict__ ws) {
    int q = blockIdx.x >> 3, p = blockIdx.x & 7;
    int c = threadIdx.x >> 3, ds = threadIdx.x & 7;
    double a = 0.0;
    if (p < q) {
        const float* wir = Wi + (q * CD_ + c) * D_;
        const float* bop = bo + p * D_;
        for (int d = ds; d < D_; d += 8) a += (double)wir[d] * (double)bop[d];
    }
    a += __shfl_xor(a, 1);
    a += __shfl_xor(a, 2);
    a += __shfl_xor(a, 4);
    if (ds == 0) ws[WS_VBP + (q * 8 + p) * 8 + c] = (float)a;
}

// ---------------- K_norm: inverse codebook norms ----------------
__global__ void k_norm(const float* __restrict__ cb, float* __restrict__ ws) {
    int id = blockIdx.x * 256 + threadIdx.x;   // 32 blocks -> 8192
    const float4* r = (const float4*)(cb + (size_t)id * CD_);
    float4 v = r[0], w = r[1];
    float ss = v.x * v.x + v.y * v.y + v.z * v.z + v.w * v.w;
    float so = w.x * w.x + w.y * w.y + w.z * w.z + w.w * w.w;
    float nrm = sqrtf(ss + so);
    ws[WS_INV + id] = 1.0f / fmaxf(nrm, 1e-12f);
}

// ---------------- K_z0: Z0[row][col] = Wi.x + (bi - vb_cum), 16 rows/thread ----------------
__global__ __launch_bounds__(256) void k_z0(const float* __restrict__ x,
                                            const float* __restrict__ Wi,
                                            const float* __restrict__ bi,
                                            float* ws) {
    int col = blockIdx.x * 256 + threadIdx.x;   // 125*256 = 32000, exact
    int rg  = blockIdx.y;                       // 0..3
    int b = col / T_;
    int t = col - b * T_;
    const float* xp = x + (size_t)b * (D_ * T_) + t;
    const float* Wr = Wi + rg * 16 * D_;        // uniform base

    double tot[16];
    #pragma unroll
    for (int r = 0; r < 16; ++r) tot[r] = 0.0;

    for (int ch = 0; ch < 8; ++ch) {
        float chk[16];
        #pragma unroll
        for (int r = 0; r < 16; ++r) chk[r] = 0.0f;
        #pragma unroll
        for (int k4 = 0; k4 < 16; ++k4) {
            int d = ch * 64 + k4 * 4;
            float x0 = xp[(size_t)(d + 0) * T_];
            float x1 = xp[(size_t)(d + 1) * T_];
            float x2 = xp[(size_t)(d + 2) * T_];
            float x3 = xp[(size_t)(d + 3) * T_];
            #pragma unroll
            for (int r = 0; r < 16; ++r) {
                const float* w = Wr + r * D_ + d;   // uniform -> SGPR
                chk[r] = fmaf(w[0], x0, fmaf(w[1], x1, fmaf(w[2], x2, fmaf(w[3], x3, chk[r]))));
            }
        }
        #pragma unroll
        for (int r = 0; r < 16; ++r) tot[r] += (double)chk[r];
    }

    #pragma unroll
    for (int r = 0; r < 16; ++r) {
        int row = rg * 16 + r;       // q*8+c
        int q = row >> 3, c = row & 7;
        float bias = bi[row];
        for (int p = 0; p < q; ++p) bias -= ws[WS_VBP + (q * 8 + p) * 8 + c];
        ws[WS_Z0 + (size_t)row * NCOL + col] = (float)tot[r] + bias;
    }
}

// ---------------- K_vq: 4 waves/block, SGPR codebook, LDS merge (R3-proven) ----------------
__global__ __launch_bounds__(256) void k_vq(const float* __restrict__ cb,
                                            float* ws, float* __restrict__ out) {
    __shared__ float s_val[4][64];
    __shared__ int   s_idx[4][64];

    int tid  = threadIdx.x;
    int wid  = tid >> 6;
    int lane = tid & 63;
    int blk  = blockIdx.x;
    int col  = blk * 64 + lane;

    const float* z0 = ws + WS_Z0;
    const float* M  = ws + WS_M;

    float zqh[Q_][CD_];
    float lossv[Q_];

    #pragma unroll
    for (int q = 0; q < Q_; ++q) {
        // z_e = Z0 - corrections (computed redundantly in every wave)
        float ze[CD_];
        #pragma unroll
        for (int c = 0; c < CD_; ++c) ze[c] = z0[(q * 8 + c) * NCOL + col];
        #pragma unroll
        for (int p = 0; p < q; ++p) {
            const float4* Mp = (const float4*)(M + (q * 8 + p) * 64);
            #pragma unroll
            for (int c = 0; c < CD_; ++c) {
                float4 a = Mp[c * 2 + 0];
                float4 bq = Mp[c * 2 + 1];
                float tc = a.x * zqh[p][0];
                tc = fmaf(a.y,  zqh[p][1], tc);
                tc = fmaf(a.z,  zqh[p][2], tc);
                tc = fmaf(a.w,  zqh[p][3], tc);
                tc = fmaf(bq.x, zqh[p][4], tc);
                tc = fmaf(bq.y, zqh[p][5], tc);
                tc = fmaf(bq.z, zqh[p][6], tc);
                tc = fmaf(bq.w, zqh[p][7], tc);
                ze[c] -= tc;
            }
        }

        // partial argmax over this wave's 256 codes (uniform scalar loads)
        const float4* cb4 = (const float4*)(cb + ((size_t)q * CS_ + wid * 256) * CD_);
        const float*  iv  = ws + WS_INV + q * CS_ + wid * 256;
        float b0 = -1e30f, b1 = -1e30f, b2 = -1e30f, b3 = -1e30f;
        int   n0 = 0, n1 = 1, n2 = 2, n3 = 3;
        for (int i = 0; i < 256; i += 4) {
            float4 a0 = cb4[(i + 0) * 2], x0 = cb4[(i + 0) * 2 + 1];
            float4 a1 = cb4[(i + 1) * 2], x1 = cb4[(i + 1) * 2 + 1];
            float4 a2 = cb4[(i + 2) * 2], x2 = cb4[(i + 2) * 2 + 1];
            float4 a3 = cb4[(i + 3) * 2], x3 = cb4[(i + 3) * 2 + 1];
            float4 iv4 = *(const float4*)(iv + i);
            float s0 = ze[0] * a0.x; s0 = fmaf(ze[1], a0.y, s0); s0 = fmaf(ze[2], a0.z, s0); s0 = fmaf(ze[3], a0.w, s0);
            s0 = fmaf(ze[4], x0.x, s0); s0 = fmaf(ze[5], x0.y, s0); s0 = fmaf(ze[6], x0.z, s0); s0 = fmaf(ze[7], x0.w, s0);
            float s1 = ze[0] * a1.x; s1 = fmaf(ze[1], a1.y, s1); s1 = fmaf(ze[2], a1.z, s1); s1 = fmaf(ze[3], a1.w, s1);
            s1 = fmaf(ze[4], x1.x, s1); s1 = fmaf(ze[5], x1.y, s1); s1 = fmaf(ze[6], x1.z, s1); s1 = fmaf(ze[7], x1.w, s1);
            float s2 = ze[0] * a2.x; s2 = fmaf(ze[1], a2.y, s2); s2 = fmaf(ze[2], a2.z, s2); s2 = fmaf(ze[3], a2.w, s2);
            s2 = fmaf(ze[4], x2.x, s2); s2 = fmaf(ze[5], x2.y, s2); s2 = fmaf(ze[6], x2.z, s2); s2 = fmaf(ze[7], x2.w, s2);
            float s3 = ze[0] * a3.x; s3 = fmaf(ze[1], a3.y, s3); s3 = fmaf(ze[2], a3.z, s3); s3 = fmaf(ze[3], a3.w, s3);
            s3 = fmaf(ze[4], x3.x, s3); s3 = fmaf(ze[5], x3.y, s3); s3 = fmaf(ze[6], x3.z, s3); s3 = fmaf(ze[7], x3.w, s3);
            s0 *= iv4.x;
            s1 *= iv4.y;
            s2 *= iv4.z;
            s3 *= iv4.w;
            if (s0 > b0) { b0 = s0; n0 = i + 0; }
            if (s1 > b1) { b1 = s1; n1 = i + 1; }
            if (s2 > b2) { b2 = s2; n2 = i + 2; }
            if (s3 > b3) { b3 = s3; n3 = i + 3; }
        }
        // merge 4 chains (tie -> lowest index)
        float bb = b0; int nn = n0;
        if (b1 > bb || (b1 == bb && n1 < nn)) { bb = b1; nn = n1; }
        if (b2 > bb || (b2 == bb && n2 < nn)) { bb = b2; nn = n2; }
        if (b3 > bb || (b3 == bb && n3 < nn)) { bb = b3; nn = n3; }
        nn += wid * 256;

        s_val[wid][lane] = bb;
        s_idx[wid][lane] = nn;
        __syncthreads();

        // cross-wave merge (redundant in all waves). Ranges increase with wid,
        // so strict > keeps the first-max index.
        float gb = s_val[0][lane]; int gn = s_idx[0][lane];
        float t1 = s_val[1][lane]; int m1 = s_idx[1][lane];
        float t2 = s_val[2][lane]; int m2 = s_idx[2][lane];
        float t3 = s_val[3][lane]; int m3 = s_idx[3][lane];
        if (t1 > gb) { gb = t1; gn = m1; }
        if (t2 > gb) { gb = t2; gn = m2; }
        if (t3 > gb) { gb = t3; gn = m3; }
        __syncthreads();

        // gather winner code vector from global (raw codebook)
        const float4* zrow = (const float4*)(cb + ((size_t)q * CS_ + gn) * CD_);
        float4 za = zrow[0], zb = zrow[1];
        zqh[q][0] = za.x; zqh[q][1] = za.y; zqh[q][2] = za.z; zqh[q][3] = za.w;
        zqh[q][4] = zb.x; zqh[q][5] = zb.y; zqh[q][6] = zb.z; zqh[q][7] = zb.w;

        if (wid == 0) {
            out[OFF_IDX + q * NCOL + col] = (float)gn;
            float l = 0.0f;
            #pragma unroll
            for (int c = 0; c < CD_; ++c) { float dd = ze[c] - zqh[q][c]; l = fmaf(dd, dd, l); }
            lossv[q] = l;
            #pragma unroll
            for (int c = 0; c < CD_; ++c) ws[WS_ZQ + (q * 8 + c) * NCOL + col] = zqh[q][c];
        } else {
            lossv[q] = 0.0f;
        }
    }

    // per-block loss partials from wave 0 (deterministic, no atomics)
    if (wid == 0) {
        #pragma unroll
        for (int q = 0; q < Q_; ++q) {
            float l = lossv[q];
            l += __shfl_xor(l, 1);
            l += __shfl_xor(l, 2);
            l += __shfl_xor(l, 4);
            l += __shfl_xor(l, 8);
            l += __shfl_xor(l, 16);
            l += __shfl_xor(l, 32);
            if (lane == 0) ws[WS_LP + q * 500 + blk] = l;
        }
    }
}

// ---------------- K_out: thread = column, 32 d-rows/block, grid (125,16) ----------------
__global__ __launch_bounds__(256) void k_out(const float* __restrict__ Wo,
                                             const float* __restrict__ bo,
                                             const float* __restrict__ ws,
                                             float* __restrict__ out) {
    int col = blockIdx.x * 256 + threadIdx.x;
    int d0  = blockIdx.y * 32;
    int b = col / T_;
    int t = col - b * T_;

    float zq[Q_][CD_];
    #pragma unroll
    for (int q = 0; q < Q_; ++q)
        #pragma unroll
        for (int c = 0; c < CD_; ++c)
            zq[q][c] = ws[WS_ZQ + (q * 8 + c) * NCOL + col];

    size_t cbase = ((size_t)b * D_) * T_ + t;
    #pragma unroll 4
    for (int dd = 0; dd < 32; ++dd) {
        int d = d0 + dd;
        float qsum = 0.0f;
        size_t dbase = cbase + (size_t)d * T_;
        #pragma unroll
        for (int q = 0; q < Q_; ++q) {
            const float* wr = Wo + (q * D_ + d) * CD_;   // uniform -> scalar loads
            float qv = bo[q * D_ + d];
            qv = fmaf(wr[0], zq[q][0], qv);
            qv = fmaf(wr[1], zq[q][1], qv);
            qv = fmaf(wr[2], zq[q][2], qv);
            qv = fmaf(wr[3], zq[q][3], qv);
            qv = fmaf(wr[4], zq[q][4], qv);
            qv = fmaf(wr[5], zq[q][5], qv);
            qv = fmaf(wr[6], zq[q][6], qv);
            qv = fmaf(wr[7], zq[q][7], qv);
            out[OFF_ALLQ + (size_t)q * (B_ * D_ * T_) + dbase] = qv;
            qsum += qv;
        }
        out[OFF_QOUT + dbase] = qsum;
    }
}

// ---------------- K_loss: finalize 8 losses from per-block partials ----------------
__global__ void k_loss(const float* __restrict__ ws, float* __restrict__ out) {
    int tid = threadIdx.x;        // 256
    int q = tid >> 5, i = tid & 31;
    double s = 0.0;
    for (int j = i; j < 500; j += 32) s += (double)ws[WS_LP + q * 500 + j];
    s += __shfl_xor(s, 1);
    s += __shfl_xor(s, 2);
    s += __shfl_xor(s, 4);
    s += __shfl_xor(s, 8);
    s += __shfl_xor(s, 16);
    if (i == 0) out[OFF_LOSS + q] = (float)(1.25 * s / 256000.0);
}

extern "C" void kernel_launch(void* const* d_in, const int* in_sizes, int n_in,
                              void* d_out, int out_size, void* d_ws, size_t ws_size,
                              hipStream_t stream) {
    const float* x  = (const float*)d_in[0];
    const float* Wi = (const float*)d_in[1];
    const float* bi = (const float*)d_in[2];
    const float* Wo = (const float*)d_in[3];
    const float* bo = (const float*)d_in[4];
    const float* cb = (const float*)d_in[5];
    float* out = (float*)d_out;
    float* ws  = (float*)d_ws;

    hipLaunchKernelGGL(k_precompute_M,   dim3(64),      dim3(64),  0, stream, Wi, Wo, ws);
    hipLaunchKernelGGL(k_precompute_vbp, dim3(64),      dim3(64),  0, stream, Wi, bo, ws);
    hipLaunchKernelGGL(k_norm,           dim3(32),      dim3(256), 0, stream, cb, ws);
    hipLaunchKernelGGL(k_z0,             dim3(125, 4),  dim3(256), 0, stream, x, Wi, bi, ws);
    hipLaunchKernelGGL(k_vq,             dim3(500),     dim3(256), 0, stream, cb, ws, out);
    hipLaunchKernelGGL(k_out,            dim3(125, 16), dim3(256), 0, stream, Wo, bo, ws, out);
    hipLaunchKernelGGL(k_loss,           dim3(1),       dim3(256), 0, stream, ws, out);
}